// Round 1
// baseline (748.592 us; speedup 1.0000x reference)
//
#include <hip/hip_runtime.h>

#define T_DIM 256
#define B_DIM 2048
#define D_IN_DIM 128
#define NQ 8

// ---------------------------------------------------------------------------
// Kernel 1: precompute Z[t][b][q][gate] = x[t][b] . Wgate[0:128, q] + b + theta
// One thread per row (t*B+b). W indices are wave-uniform -> scalar loads.
// ---------------------------------------------------------------------------
__global__ __launch_bounds__(256) void qlstm_gemm(
    const float* __restrict__ X,   // [rows][128], chunk base
    const float* __restrict__ Wf, const float* __restrict__ Wi,
    const float* __restrict__ Wg, const float* __restrict__ Wo,
    const float* __restrict__ bf, const float* __restrict__ bi,
    const float* __restrict__ bg, const float* __restrict__ bo,
    const float* __restrict__ thf, const float* __restrict__ thi,
    const float* __restrict__ thg, const float* __restrict__ tho,
    float* __restrict__ Z, int rows)
{
    int row = blockIdx.x * blockDim.x + threadIdx.x;
    if (row >= rows) return;
    const float4* xrow = (const float4*)(X + (size_t)row * D_IN_DIM);

    float acc[32];
#pragma unroll
    for (int q = 0; q < NQ; q++) {
        acc[q * 4 + 0] = bf[q] + thf[q];
        acc[q * 4 + 1] = bi[q] + thi[q];
        acc[q * 4 + 2] = bg[q] + thg[q];
        acc[q * 4 + 3] = bo[q] + tho[q];
    }

#pragma unroll 1
    for (int j4 = 0; j4 < D_IN_DIM / 4; j4++) {
        float4 xv = xrow[j4];
        float xs[4] = {xv.x, xv.y, xv.z, xv.w};
#pragma unroll
        for (int jj = 0; jj < 4; jj++) {
            int j = j4 * 4 + jj;
            float xj = xs[jj];
#pragma unroll
            for (int q = 0; q < NQ; q++) {
                acc[q * 4 + 0] += xj * Wf[j * NQ + q];
                acc[q * 4 + 1] += xj * Wi[j * NQ + q];
                acc[q * 4 + 2] += xj * Wg[j * NQ + q];
                acc[q * 4 + 3] += xj * Wo[j * NQ + q];
            }
        }
    }

    float4* zrow = (float4*)(Z + (size_t)row * 32);
#pragma unroll
    for (int q = 0; q < NQ; q++) {
        zrow[q] = make_float4(acc[q * 4 + 0], acc[q * 4 + 1],
                              acc[q * 4 + 2], acc[q * 4 + 3]);
    }
}

// ---------------------------------------------------------------------------
// Kernel 2: sequential recurrence. Thread = (b, q); 8 lanes per batch elem.
// ---------------------------------------------------------------------------
__device__ __forceinline__ float fast_cos(float x)  { return __cosf(x); }
__device__ __forceinline__ float fast_sig(float x)  { return 1.0f / (1.0f + __expf(-x)); }
__device__ __forceinline__ float fast_tanh(float x) { return 1.0f - 2.0f / (__expf(2.0f * x) + 1.0f); }

__global__ __launch_bounds__(256) void qlstm_recur(
    const float* __restrict__ Z,   // chunk base, [ct][B][8 float4]
    const float* __restrict__ Wf, const float* __restrict__ Wi,
    const float* __restrict__ Wg, const float* __restrict__ Wo,
    float* __restrict__ out,       // full output base
    float* __restrict__ state,     // [h: B*8][c: B*8]
    int t0, int ct, int first, int last)
{
    int tid = blockIdx.x * blockDim.x + threadIdx.x;  // 0..16383
    int b = tid >> 3;
    int q = tid & 7;
    int lane = (int)(threadIdx.x & 63);
    int base = lane & ~7;

    // Recurrent weight columns for this q: rows 128..135 of each W.
    float whf[8], whi[8], whg[8], who[8];
#pragma unroll
    for (int j = 0; j < 8; j++) {
        whf[j] = Wf[(D_IN_DIM + j) * NQ + q];
        whi[j] = Wi[(D_IN_DIM + j) * NQ + q];
        whg[j] = Wg[(D_IN_DIM + j) * NQ + q];
        who[j] = Wo[(D_IN_DIM + j) * NQ + q];
    }

    float h, c;
    if (first) { h = 0.0f; c = 0.0f; }
    else {
        h = state[b * NQ + q];
        c = state[B_DIM * NQ + b * NQ + q];
    }

    const float4* Zp = (const float4*)Z;
    size_t zidx = (size_t)b * NQ + q;          // row stride is B*8 float4s
    float4 z = Zp[zidx];

    for (int tl = 0; tl < ct; tl++) {
        float4 zn = (tl + 1 < ct) ? Zp[(size_t)(tl + 1) * B_DIM * NQ + zidx] : z;

        float accf = z.x, acci = z.y, accg = z.z, acco = z.w;
#pragma unroll
        for (int j = 0; j < 8; j++) {
            float hj = __shfl(h, base + j, 64);
            accf += hj * whf[j];
            acci += hj * whi[j];
            accg += hj * whg[j];
            acco += hj * who[j];
        }

        float fg = fast_sig(fast_cos(accf));
        float ig = fast_sig(fast_cos(acci));
        float gg = fast_tanh(fast_cos(accg));
        float og = fast_sig(fast_cos(acco));

        c = fg * c + ig * gg;
        float tc = fast_tanh(c);
        h = og * tc;

        out[((size_t)(t0 + tl) * B_DIM + b) * NQ + q] = h;
        z = zn;
    }

    if (last) {
        out[(size_t)T_DIM * B_DIM * NQ + (size_t)b * NQ + q] = h;
        out[(size_t)T_DIM * B_DIM * NQ + (size_t)B_DIM * NQ + (size_t)b * NQ + q] = c;
    } else {
        state[b * NQ + q] = h;
        state[B_DIM * NQ + b * NQ + q] = c;
    }
}

// ---------------------------------------------------------------------------
extern "C" void kernel_launch(void* const* d_in, const int* in_sizes, int n_in,
                              void* d_out, int out_size, void* d_ws, size_t ws_size,
                              hipStream_t stream) {
    const float* X   = (const float*)d_in[0];
    const float* Wf  = (const float*)d_in[1];
    const float* bf  = (const float*)d_in[2];
    const float* Wi  = (const float*)d_in[3];
    const float* bi  = (const float*)d_in[4];
    const float* Wg  = (const float*)d_in[5];
    const float* bg  = (const float*)d_in[6];
    const float* Wo  = (const float*)d_in[7];
    const float* bo  = (const float*)d_in[8];
    const float* thf = (const float*)d_in[9];
    const float* thi = (const float*)d_in[10];
    const float* thg = (const float*)d_in[11];
    const float* tho = (const float*)d_in[12];
    float* out = (float*)d_out;

    // ws layout: [state: 2*B*NQ floats][Z chunk buffer]
    const size_t state_bytes = (size_t)2 * B_DIM * NQ * sizeof(float);  // 128 KiB
    float* state = (float*)d_ws;
    float* Zbuf  = (float*)((char*)d_ws + state_bytes);
    size_t avail = ws_size > state_bytes ? ws_size - state_bytes : 0;
    const size_t z_bytes_per_t = (size_t)B_DIM * 32 * sizeof(float);    // 256 KiB
    int maxChunkT = (int)(avail / z_bytes_per_t);
    if (maxChunkT > T_DIM) maxChunkT = T_DIM;
    if (maxChunkT < 1) maxChunkT = 1;  // ws assumed >= ~384 KiB

    int t0 = 0;
    int first = 1;
    while (t0 < T_DIM) {
        int ct = (T_DIM - t0 < maxChunkT) ? (T_DIM - t0) : maxChunkT;
        int rows = ct * B_DIM;
        qlstm_gemm<<<(rows + 255) / 256, 256, 0, stream>>>(
            X + (size_t)t0 * B_DIM * D_IN_DIM,
            Wf, Wi, Wg, Wo, bf, bi, bg, bo, thf, thi, thg, tho,
            Zbuf, rows);
        int last = (t0 + ct == T_DIM) ? 1 : 0;
        qlstm_recur<<<(B_DIM * NQ) / 256, 256, 0, stream>>>(
            Zbuf, Wf, Wi, Wg, Wo, out, state, t0, ct, first, last);
        t0 += ct;
        first = 0;
    }
}

// Round 2
// 501.767 us; speedup vs baseline: 1.4919x; 1.4919x over previous
//
#include <hip/hip_runtime.h>

#define T_DIM 256
#define B_DIM 2048
#define D_IN_DIM 128
#define NQ 8
#define ROWS_PER_BLK 64
#define XSTRIDE 129   // 128 + 1 pad: LDS bank = (row + k) % 32 -> 2-way, free

// ---------------------------------------------------------------------------
// Kernel 1: Z[g][row][q] = x[row] . Wg[0:128, q] + b_g[q] + th_g[q]
// Block = 256 threads = 4 waves; block stages 64 rows of X into LDS with
// fully-coalesced float4 loads; wave w computes gate w for all 64 rows
// (lane = row). Gate pointer made wave-uniform via readfirstlane so W[k*8+q]
// compiles to scalar loads (k uniform, q unrolled).
// ---------------------------------------------------------------------------
__global__ __launch_bounds__(256) void qlstm_gemm(
    const float* __restrict__ X,   // chunk base, [rows][128]
    const float* __restrict__ Wf, const float* __restrict__ Wi,
    const float* __restrict__ Wg, const float* __restrict__ Wo,
    const float* __restrict__ bf, const float* __restrict__ bi,
    const float* __restrict__ bg, const float* __restrict__ bo,
    const float* __restrict__ thf, const float* __restrict__ thi,
    const float* __restrict__ thg, const float* __restrict__ tho,
    float* __restrict__ Z, int plane_stride)   // plane_stride = rows*NQ
{
    __shared__ float xs[ROWS_PER_BLK * XSTRIDE];

    const int t = (int)threadIdx.x;
    const int r0 = (int)blockIdx.x * ROWS_PER_BLK;

    // Stage 64 rows x 128 floats = 2048 float4, 8 per thread, coalesced.
    const float4* Xg = (const float4*)(X + (size_t)r0 * D_IN_DIM);
#pragma unroll
    for (int i = 0; i < 8; i++) {
        int L = t + i * 256;          // linear float4 index
        float4 v = Xg[L];
        int row = L >> 5;             // 32 float4 per row
        int k4  = L & 31;
        float* d = &xs[row * XSTRIDE + k4 * 4];
        d[0] = v.x; d[1] = v.y; d[2] = v.z; d[3] = v.w;
    }
    __syncthreads();

    const int wid  = __builtin_amdgcn_readfirstlane(t >> 6);  // wave id = gate
    const int lane = t & 63;                                   // = row in tile

    const float* W  = (wid == 0) ? Wf  : (wid == 1) ? Wi  : (wid == 2) ? Wg  : Wo;
    const float* BB = (wid == 0) ? bf  : (wid == 1) ? bi  : (wid == 2) ? bg  : bo;
    const float* TH = (wid == 0) ? thf : (wid == 1) ? thi : (wid == 2) ? thg : tho;

    float acc[NQ];
#pragma unroll
    for (int q = 0; q < NQ; q++) acc[q] = BB[q] + TH[q];

    const float* xrow = &xs[lane * XSTRIDE];
#pragma unroll 4
    for (int k = 0; k < D_IN_DIM; k++) {
        float xk = xrow[k];
#pragma unroll
        for (int q = 0; q < NQ; q++)
            acc[q] += xk * W[k * NQ + q];
    }

    // Store plane-major: Z[g][row][q], 32B contiguous per thread.
    float* Zg = Z + (size_t)wid * plane_stride + (size_t)(r0 + lane) * NQ;
    ((float4*)Zg)[0] = make_float4(acc[0], acc[1], acc[2], acc[3]);
    ((float4*)Zg)[1] = make_float4(acc[4], acc[5], acc[6], acc[7]);
}

// ---------------------------------------------------------------------------
// Kernel 2: sequential recurrence. 64-thread blocks -> 256 blocks -> all CUs.
// Thread = (b, q); the 8 h-values of a batch element sit in 8 adjacent lanes.
// Gate-plane Z reads are coalesced b32; prefetch depth 2 hides LLC latency.
// ---------------------------------------------------------------------------
__device__ __forceinline__ float fast_sig(float x)  { return 1.0f / (1.0f + __expf(-x)); }
__device__ __forceinline__ float fast_tanh(float x) { return 1.0f - 2.0f / (__expf(2.0f * x) + 1.0f); }

__global__ __launch_bounds__(64) void qlstm_recur(
    const float* __restrict__ Z,   // chunk base, 4 planes of [ct*B][8]
    const float* __restrict__ Wf, const float* __restrict__ Wi,
    const float* __restrict__ Wg, const float* __restrict__ Wo,
    float* __restrict__ out,       // full output base
    float* __restrict__ state,     // [h: B*8][c: B*8]
    int t0, int ct, int plane_stride, int first, int last)
{
    const int tid  = (int)blockIdx.x * 64 + (int)threadIdx.x;  // 0..16383
    const int b    = tid >> 3;
    const int q    = tid & 7;
    const int base = ((int)threadIdx.x) & ~7;

    float whf[8], whi[8], whg[8], who[8];
#pragma unroll
    for (int j = 0; j < 8; j++) {
        whf[j] = Wf[(D_IN_DIM + j) * NQ + q];
        whi[j] = Wi[(D_IN_DIM + j) * NQ + q];
        whg[j] = Wg[(D_IN_DIM + j) * NQ + q];
        who[j] = Wo[(D_IN_DIM + j) * NQ + q];
    }

    float h, c;
    if (first) { h = 0.0f; c = 0.0f; }
    else       { h = state[tid]; c = state[B_DIM * NQ + tid]; }

    const float* Zp = Z + tid;
    const size_t ps = (size_t)plane_stride;
    const size_t stepsz = (size_t)B_DIM * NQ;  // 16384

    // prefetch pipeline: slot0 = t, slot1 = t+1
    float cf0 = Zp[0], ci0 = Zp[ps], cg0 = Zp[2 * ps], co0 = Zp[3 * ps];
    size_t o1 = (ct > 1) ? stepsz : 0;
    float cf1 = Zp[o1], ci1 = Zp[ps + o1], cg1 = Zp[2 * ps + o1], co1 = Zp[3 * ps + o1];

    for (int tl = 0; tl < ct; tl++) {
        int tn = (tl + 2 < ct) ? (tl + 2) : (ct - 1);
        size_t on = (size_t)tn * stepsz;
        float nf = Zp[on], ni = Zp[ps + on], ng = Zp[2 * ps + on], no = Zp[3 * ps + on];

        float accf = cf0, acci = ci0, accg = cg0, acco = co0;
#pragma unroll
        for (int j = 0; j < 8; j++) {
            float hj = __shfl(h, base + j, 64);
            accf += hj * whf[j];
            acci += hj * whi[j];
            accg += hj * whg[j];
            acco += hj * who[j];
        }

        float fg = fast_sig(__cosf(accf));
        float ig = fast_sig(__cosf(acci));
        float gg = fast_tanh(__cosf(accg));
        float og = fast_sig(__cosf(acco));

        c = fg * c + ig * gg;
        h = og * fast_tanh(c);

        out[(size_t)(t0 + tl) * stepsz + tid] = h;

        cf0 = cf1; ci0 = ci1; cg0 = cg1; co0 = co1;
        cf1 = nf;  ci1 = ni;  cg1 = ng;  co1 = no;
    }

    if (last) {
        out[(size_t)T_DIM * stepsz + tid] = h;
        out[(size_t)T_DIM * stepsz + stepsz + tid] = c;
    } else {
        state[tid] = h;
        state[B_DIM * NQ + tid] = c;
    }
}

// ---------------------------------------------------------------------------
extern "C" void kernel_launch(void* const* d_in, const int* in_sizes, int n_in,
                              void* d_out, int out_size, void* d_ws, size_t ws_size,
                              hipStream_t stream) {
    const float* X   = (const float*)d_in[0];
    const float* Wf  = (const float*)d_in[1];
    const float* bf  = (const float*)d_in[2];
    const float* Wi  = (const float*)d_in[3];
    const float* bi  = (const float*)d_in[4];
    const float* Wg  = (const float*)d_in[5];
    const float* bg  = (const float*)d_in[6];
    const float* Wo  = (const float*)d_in[7];
    const float* bo  = (const float*)d_in[8];
    const float* thf = (const float*)d_in[9];
    const float* thi = (const float*)d_in[10];
    const float* thg = (const float*)d_in[11];
    const float* tho = (const float*)d_in[12];
    float* out = (float*)d_out;

    const size_t state_bytes = (size_t)2 * B_DIM * NQ * sizeof(float);  // 128 KiB
    float* state = (float*)d_ws;
    float* Zbuf  = (float*)((char*)d_ws + state_bytes);
    size_t avail = ws_size > state_bytes ? ws_size - state_bytes : 0;
    const size_t z_bytes_per_t = (size_t)B_DIM * 32 * sizeof(float);    // 256 KiB
    int maxChunkT = (int)(avail / z_bytes_per_t);
    if (maxChunkT > T_DIM) maxChunkT = T_DIM;
    if (maxChunkT < 1) maxChunkT = 1;

    int t0 = 0;
    int first = 1;
    while (t0 < T_DIM) {
        int ct = (T_DIM - t0 < maxChunkT) ? (T_DIM - t0) : maxChunkT;
        int rows = ct * B_DIM;
        int plane_stride = rows * NQ;
        qlstm_gemm<<<rows / ROWS_PER_BLK, 256, 0, stream>>>(
            X + (size_t)t0 * B_DIM * D_IN_DIM,
            Wf, Wi, Wg, Wo, bf, bi, bg, bo, thf, thi, thg, tho,
            Zbuf, plane_stride);
        int last = (t0 + ct == T_DIM) ? 1 : 0;
        qlstm_recur<<<(B_DIM * NQ) / 64, 64, 0, stream>>>(
            Zbuf, Wf, Wi, Wg, Wo, out, state, t0, ct, plane_stride, first, last);
        t0 += ct;
        first = 0;
    }
}

// Round 3
// 496.546 us; speedup vs baseline: 1.5076x; 1.0105x over previous
//
#include <hip/hip_runtime.h>

#define T_DIM 256
#define B_DIM 2048
#define D_IN_DIM 128
#define NQ 8
#define ROWS_PER_BLK 64
#define XSTRIDE 129   // X tile pad: bank = (row + k) % 32 -> 2-way, free
#define TSTRIDE 33    // transpose tile pad: bank = (row + c) % 32 -> 2-way, free

// ---------------------------------------------------------------------------
// Kernel 1: Z[row][q] = float4(f,i,g,o) of x[row].Wg[:,q] + b_g[q] + th_g[q]
// Block = 256 thr = 4 waves; wave = gate, lane = row-in-tile. X staged in LDS
// (coalesced float4), W streamed through scalar loads (wave-uniform index),
// epilogue transposes through LDS so the global store is coalesced float4 in
// the recurrence-friendly [row][q][gate] layout.
// ---------------------------------------------------------------------------
__global__ __launch_bounds__(256) void qlstm_gemm(
    const float* __restrict__ X,   // chunk base, [rows][128]
    const float* __restrict__ Wf, const float* __restrict__ Wi,
    const float* __restrict__ Wg, const float* __restrict__ Wo,
    const float* __restrict__ bf, const float* __restrict__ bi,
    const float* __restrict__ bg, const float* __restrict__ bo,
    const float* __restrict__ thf, const float* __restrict__ thi,
    const float* __restrict__ thg, const float* __restrict__ tho,
    float4* __restrict__ Z)        // [rows][8] float4
{
    __shared__ float xs[ROWS_PER_BLK * XSTRIDE];   // 33 KB, reused for transpose

    const int t = (int)threadIdx.x;
    const int r0 = (int)blockIdx.x * ROWS_PER_BLK;

    // Stage 64 rows x 128 floats = 2048 float4, 8 per thread, coalesced.
    const float4* Xg = (const float4*)(X + (size_t)r0 * D_IN_DIM);
#pragma unroll
    for (int i = 0; i < 8; i++) {
        int L = t + i * 256;
        float4 v = Xg[L];
        int row = L >> 5;
        int k4  = L & 31;
        float* d = &xs[row * XSTRIDE + k4 * 4];
        d[0] = v.x; d[1] = v.y; d[2] = v.z; d[3] = v.w;
    }
    __syncthreads();

    const int wid  = __builtin_amdgcn_readfirstlane(t >> 6);  // wave id = gate
    const int lane = t & 63;                                   // row in tile

    const float* W  = (wid == 0) ? Wf  : (wid == 1) ? Wi  : (wid == 2) ? Wg  : Wo;
    const float* BB = (wid == 0) ? bf  : (wid == 1) ? bi  : (wid == 2) ? bg  : bo;
    const float* TH = (wid == 0) ? thf : (wid == 1) ? thi : (wid == 2) ? thg : tho;

    float acc[NQ];
#pragma unroll
    for (int q = 0; q < NQ; q++) acc[q] = BB[q] + TH[q];

    const float* xrow = &xs[lane * XSTRIDE];
#pragma unroll 4
    for (int k = 0; k < D_IN_DIM; k++) {
        float xk = xrow[k];
#pragma unroll
        for (int q = 0; q < NQ; q++)
            acc[q] += xk * W[k * NQ + q];
    }

    // Transpose through LDS (reuse xs) -> coalesced float4 stores.
    __syncthreads();
    float* tile = xs;   // [64][TSTRIDE], elem (r, q*4+g)
#pragma unroll
    for (int q = 0; q < NQ; q++)
        tile[lane * TSTRIDE + q * 4 + wid] = acc[q];
    __syncthreads();

    float4* Zblk = Z + (size_t)r0 * NQ;
#pragma unroll
    for (int i = 0; i < 2; i++) {
        int F = t + i * 256;          // float4 index: r = F>>3, q = F&7
        int r = F >> 3, q = F & 7;
        const float* s = &tile[r * TSTRIDE + q * 4];
        Zblk[F] = make_float4(s[0], s[1], s[2], s[3]);
    }
}

// ---------------------------------------------------------------------------
// Kernel 2: sequential recurrence. 256 blocks x 64 thr (1 wave/CU).
// Thread = (b,q). One float4 Z load per step, register prefetch pipeline of
// depth 8 (~1600 cyc slack > 900 cyc HBM). h broadcast within groups of 8
// lanes via ds_swizzle with immediate pattern (no address setup).
// ---------------------------------------------------------------------------
__device__ __forceinline__ float fast_sig(float x)  { return 1.0f / (1.0f + __expf(-x)); }
__device__ __forceinline__ float fast_tanh(float x) { return 1.0f - 2.0f / (__expf(2.0f * x) + 1.0f); }

#define BCAST8(x, J) \
    __int_as_float(__builtin_amdgcn_ds_swizzle(__float_as_int(x), ((J) << 5) | 0x18))

#define DOT_TERM(J) { \
    float hj = BCAST8(h, J); \
    accf += hj * whf[J]; acci += hj * whi[J]; \
    accg += hj * whg[J]; acco += hj * who[J]; }

#define LSTM_STEP(zv, outp) { \
    float accf = (zv).x, acci = (zv).y, accg = (zv).z, acco = (zv).w; \
    DOT_TERM(0) DOT_TERM(1) DOT_TERM(2) DOT_TERM(3) \
    DOT_TERM(4) DOT_TERM(5) DOT_TERM(6) DOT_TERM(7) \
    float fg = fast_sig(__cosf(accf)); \
    float ig = fast_sig(__cosf(acci)); \
    float gg = fast_tanh(__cosf(accg)); \
    float og = fast_sig(__cosf(acco)); \
    c = fg * c + ig * gg; \
    h = og * fast_tanh(c); \
    *(outp) = h; }

__global__ __launch_bounds__(64) void qlstm_recur(
    const float4* __restrict__ Z,  // chunk base, [ct][B*NQ] float4
    const float* __restrict__ Wf, const float* __restrict__ Wi,
    const float* __restrict__ Wg, const float* __restrict__ Wo,
    float* __restrict__ out,       // full output base
    float* __restrict__ state,     // [h: B*8][c: B*8]
    int t0, int ct, int first, int last)
{
    const int tid = (int)blockIdx.x * 64 + (int)threadIdx.x;  // 0..16383
    const int q   = tid & 7;

    float whf[8], whi[8], whg[8], who[8];
#pragma unroll
    for (int j = 0; j < 8; j++) {
        whf[j] = Wf[(D_IN_DIM + j) * NQ + q];
        whi[j] = Wi[(D_IN_DIM + j) * NQ + q];
        whg[j] = Wg[(D_IN_DIM + j) * NQ + q];
        who[j] = Wo[(D_IN_DIM + j) * NQ + q];
    }

    float h, c;
    if (first) { h = 0.0f; c = 0.0f; }
    else       { h = state[tid]; c = state[B_DIM * NQ + tid]; }

    const size_t stepsz = (size_t)B_DIM * NQ;   // 16384 (float4s per t; floats per t for out)
    const float4* Zp = Z + tid;
    float* outp = out + (size_t)t0 * stepsz + tid;

    // Prologue: fill depth-8 pipeline (ct is always a multiple of 8, >= 8).
    float4 buf[8];
#pragma unroll
    for (int s = 0; s < 8; s++) buf[s] = Zp[(size_t)s * stepsz];

    int tb = 0;
    for (; tb + 8 < ct; tb += 8) {
#pragma unroll
        for (int s = 0; s < 8; s++) {
            float4 nz = Zp[(size_t)(tb + s + 8) * stepsz];  // issue early
            float4 z = buf[s];
            LSTM_STEP(z, outp)
            outp += stepsz;
            buf[s] = nz;   // register rename; vmcnt wait lands 8 steps later
        }
    }
    // Epilogue: last 8 steps, no prefetch.
#pragma unroll
    for (int s = 0; s < 8; s++) {
        float4 z = buf[s];
        LSTM_STEP(z, outp)
        outp += stepsz;
    }

    if (last) {
        out[(size_t)T_DIM * stepsz + tid] = h;
        out[(size_t)T_DIM * stepsz + stepsz + tid] = c;
    } else {
        state[tid] = h;
        state[B_DIM * NQ + tid] = c;
    }
}

// ---------------------------------------------------------------------------
extern "C" void kernel_launch(void* const* d_in, const int* in_sizes, int n_in,
                              void* d_out, int out_size, void* d_ws, size_t ws_size,
                              hipStream_t stream) {
    const float* X   = (const float*)d_in[0];
    const float* Wf  = (const float*)d_in[1];
    const float* bf  = (const float*)d_in[2];
    const float* Wi  = (const float*)d_in[3];
    const float* bi  = (const float*)d_in[4];
    const float* Wg  = (const float*)d_in[5];
    const float* bg  = (const float*)d_in[6];
    const float* Wo  = (const float*)d_in[7];
    const float* bo  = (const float*)d_in[8];
    const float* thf = (const float*)d_in[9];
    const float* thi = (const float*)d_in[10];
    const float* thg = (const float*)d_in[11];
    const float* tho = (const float*)d_in[12];
    float* out = (float*)d_out;

    const size_t state_bytes = (size_t)2 * B_DIM * NQ * sizeof(float);  // 128 KiB
    float* state = (float*)d_ws;
    float4* Zbuf = (float4*)((char*)d_ws + state_bytes);
    size_t avail = ws_size > state_bytes ? ws_size - state_bytes : 0;
    const size_t z_bytes_per_t = (size_t)B_DIM * NQ * sizeof(float4);   // 256 KiB
    int maxChunkT = (int)(avail / z_bytes_per_t);
    if (maxChunkT > T_DIM) maxChunkT = T_DIM;
    maxChunkT &= ~7;                 // recur requires multiples of 8
    if (maxChunkT < 8) maxChunkT = 8; // ws assumed >= ~2.2 MiB

    int t0 = 0;
    int first = 1;
    while (t0 < T_DIM) {
        int ct = (T_DIM - t0 < maxChunkT) ? (T_DIM - t0) : maxChunkT;
        int rows = ct * B_DIM;
        qlstm_gemm<<<rows / ROWS_PER_BLK, 256, 0, stream>>>(
            X + (size_t)t0 * B_DIM * D_IN_DIM,
            Wf, Wi, Wg, Wo, bf, bi, bg, bo, thf, thi, thg, tho,
            Zbuf);
        int last = (t0 + ct == T_DIM) ? 1 : 0;
        qlstm_recur<<<(B_DIM * NQ) / 64, 64, 0, stream>>>(
            Zbuf, Wf, Wi, Wg, Wo, out, state, t0, ct, first, last);
        t0 += ct;
        first = 0;
    }
}

// Round 4
// 487.099 us; speedup vs baseline: 1.5368x; 1.0194x over previous
//
#include <hip/hip_runtime.h>

#define T_DIM 256
#define B_DIM 2048
#define D_IN_DIM 128
#define NQ 8
#define ROWS_PER_BLK 64
#define XSTRIDE 129   // X tile pad: bank = (row + k) % 32 -> 2-way, free
#define TSTRIDE 33    // transpose tile pad: 2-way, free

// ---------------------------------------------------------------------------
// Kernel 1: Z[row][q] = float4(f,i,g,o) of x[row].Wg[:,q] + b_g[q] + th_g[q]
// Block = 256 thr = 4 waves; wave = gate, lane = row-in-tile. X staged in LDS
// (coalesced float4), W streamed through scalar loads (wave-uniform index),
// epilogue transposes through LDS so the global store is coalesced float4 in
// the recurrence-friendly [row][q][gate] layout.
// ---------------------------------------------------------------------------
__global__ __launch_bounds__(256) void qlstm_gemm(
    const float* __restrict__ X,   // chunk base, [rows][128]
    const float* __restrict__ Wf, const float* __restrict__ Wi,
    const float* __restrict__ Wg, const float* __restrict__ Wo,
    const float* __restrict__ bf, const float* __restrict__ bi,
    const float* __restrict__ bg, const float* __restrict__ bo,
    const float* __restrict__ thf, const float* __restrict__ thi,
    const float* __restrict__ thg, const float* __restrict__ tho,
    float4* __restrict__ Z)        // [rows][8] float4
{
    __shared__ float xs[ROWS_PER_BLK * XSTRIDE];   // 33 KB, reused for transpose

    const int t = (int)threadIdx.x;
    const int r0 = (int)blockIdx.x * ROWS_PER_BLK;

    const float4* Xg = (const float4*)(X + (size_t)r0 * D_IN_DIM);
#pragma unroll
    for (int i = 0; i < 8; i++) {
        int L = t + i * 256;
        float4 v = Xg[L];
        int row = L >> 5;
        int k4  = L & 31;
        float* d = &xs[row * XSTRIDE + k4 * 4];
        d[0] = v.x; d[1] = v.y; d[2] = v.z; d[3] = v.w;
    }
    __syncthreads();

    const int wid  = __builtin_amdgcn_readfirstlane(t >> 6);  // wave id = gate
    const int lane = t & 63;                                   // row in tile

    const float* W  = (wid == 0) ? Wf  : (wid == 1) ? Wi  : (wid == 2) ? Wg  : Wo;
    const float* BB = (wid == 0) ? bf  : (wid == 1) ? bi  : (wid == 2) ? bg  : bo;
    const float* TH = (wid == 0) ? thf : (wid == 1) ? thi : (wid == 2) ? thg : tho;

    float acc[NQ];
#pragma unroll
    for (int q = 0; q < NQ; q++) acc[q] = BB[q] + TH[q];

    const float* xrow = &xs[lane * XSTRIDE];
#pragma unroll 4
    for (int k = 0; k < D_IN_DIM; k++) {
        float xk = xrow[k];
#pragma unroll
        for (int q = 0; q < NQ; q++)
            acc[q] += xk * W[k * NQ + q];
    }

    __syncthreads();
    float* tile = xs;   // [64][TSTRIDE], elem (r, q*4+g)
#pragma unroll
    for (int q = 0; q < NQ; q++)
        tile[lane * TSTRIDE + q * 4 + wid] = acc[q];
    __syncthreads();

    float4* Zblk = Z + (size_t)r0 * NQ;
#pragma unroll
    for (int i = 0; i < 2; i++) {
        int F = t + i * 256;          // float4 index: r = F>>3, q = F&7
        int r = F >> 3, q = F & 7;
        const float* s = &tile[r * TSTRIDE + q * 4];
        Zblk[F] = make_float4(s[0], s[1], s[2], s[3]);
    }
}

// ---------------------------------------------------------------------------
// Kernel 2: sequential recurrence. 256 blocks x 64 thr (1 wave/CU).
// Thread = (b,q). One float4 Z load per step. TRUE ping-pong register double
// buffer: phase loads land in the buffer consumed 8 steps later, so the
// s_waitcnt for a load fires ~8 steps (~1400 cyc) after issue, covering HBM
// latency. (Previous rounds' rolling buffer forced the wait in-step.)
// ---------------------------------------------------------------------------
__device__ __forceinline__ float fast_sig(float x)  { return 1.0f / (1.0f + __expf(-x)); }
__device__ __forceinline__ float fast_tanh(float x) { return 1.0f - 2.0f / (__expf(2.0f * x) + 1.0f); }

#define BCAST8(x, J) \
    __int_as_float(__builtin_amdgcn_ds_swizzle(__float_as_int(x), ((J) << 5) | 0x18))

#define DOT_TERM(J) { \
    float hj = BCAST8(h, J); \
    accf += hj * whf[J]; acci += hj * whi[J]; \
    accg += hj * whg[J]; acco += hj * who[J]; }

#define LSTM_STEP(zv, outp) { \
    float accf = (zv).x, acci = (zv).y, accg = (zv).z, acco = (zv).w; \
    DOT_TERM(0) DOT_TERM(1) DOT_TERM(2) DOT_TERM(3) \
    DOT_TERM(4) DOT_TERM(5) DOT_TERM(6) DOT_TERM(7) \
    float fg = fast_sig(__cosf(accf)); \
    float ig = fast_sig(__cosf(acci)); \
    float gg = fast_tanh(__cosf(accg)); \
    float og = fast_sig(__cosf(acco)); \
    c = fg * c + ig * gg; \
    h = og * fast_tanh(c); \
    *(outp) = h; }

__global__ __launch_bounds__(64) void qlstm_recur(
    const float4* __restrict__ Z,  // chunk base, [ct][B*NQ] float4
    const float* __restrict__ Wf, const float* __restrict__ Wi,
    const float* __restrict__ Wg, const float* __restrict__ Wo,
    float* __restrict__ out,       // full output base
    float* __restrict__ state,     // [h: B*8][c: B*8]
    int t0, int ct, int first, int last)
{
    const int tid = (int)blockIdx.x * 64 + (int)threadIdx.x;  // 0..16383
    const int q   = tid & 7;

    float whf[8], whi[8], whg[8], who[8];
#pragma unroll
    for (int j = 0; j < 8; j++) {
        whf[j] = Wf[(D_IN_DIM + j) * NQ + q];
        whi[j] = Wi[(D_IN_DIM + j) * NQ + q];
        whg[j] = Wg[(D_IN_DIM + j) * NQ + q];
        who[j] = Wo[(D_IN_DIM + j) * NQ + q];
    }

    float h, c;
    if (first) { h = 0.0f; c = 0.0f; }
    else       { h = state[tid]; c = state[B_DIM * NQ + tid]; }

    const size_t stepsz = (size_t)B_DIM * NQ;   // 16384
    const float4* Zp = Z + tid;
    float* outp = out + (size_t)t0 * stepsz + tid;

    float4 bufA[8], bufB[8];
    // Prologue: fill A with steps 0..7 (ct is a multiple of 16, >= 16).
#pragma unroll
    for (int s = 0; s < 8; s++) bufA[s] = Zp[(size_t)s * stepsz];

    for (int tb = 0; tb < ct; tb += 16) {
        // Issue loads for steps tb+8..tb+15 into B (always in range).
#pragma unroll
        for (int s = 0; s < 8; s++) bufB[s] = Zp[(size_t)(tb + 8 + s) * stepsz];
        // Consume A: steps tb..tb+7 (no dependence on B's in-flight loads).
#pragma unroll
        for (int s = 0; s < 8; s++) {
            float4 z = bufA[s];
            LSTM_STEP(z, outp)
            outp += stepsz;
        }
        // Issue loads for steps tb+16..tb+23 into A (skip on last group).
        if (tb + 16 < ct) {
#pragma unroll
            for (int s = 0; s < 8; s++) bufA[s] = Zp[(size_t)(tb + 16 + s) * stepsz];
        }
        // Consume B: steps tb+8..tb+15.
#pragma unroll
        for (int s = 0; s < 8; s++) {
            float4 z = bufB[s];
            LSTM_STEP(z, outp)
            outp += stepsz;
        }
    }

    if (last) {
        out[(size_t)T_DIM * stepsz + tid] = h;
        out[(size_t)T_DIM * stepsz + stepsz + tid] = c;
    } else {
        state[tid] = h;
        state[B_DIM * NQ + tid] = c;
    }
}

// ---------------------------------------------------------------------------
extern "C" void kernel_launch(void* const* d_in, const int* in_sizes, int n_in,
                              void* d_out, int out_size, void* d_ws, size_t ws_size,
                              hipStream_t stream) {
    const float* X   = (const float*)d_in[0];
    const float* Wf  = (const float*)d_in[1];
    const float* bf  = (const float*)d_in[2];
    const float* Wi  = (const float*)d_in[3];
    const float* bi  = (const float*)d_in[4];
    const float* Wg  = (const float*)d_in[5];
    const float* bg  = (const float*)d_in[6];
    const float* Wo  = (const float*)d_in[7];
    const float* bo  = (const float*)d_in[8];
    const float* thf = (const float*)d_in[9];
    const float* thi = (const float*)d_in[10];
    const float* thg = (const float*)d_in[11];
    const float* tho = (const float*)d_in[12];
    float* out = (float*)d_out;

    const size_t state_bytes = (size_t)2 * B_DIM * NQ * sizeof(float);  // 128 KiB
    float* state = (float*)d_ws;
    float4* Zbuf = (float4*)((char*)d_ws + state_bytes);
    size_t avail = ws_size > state_bytes ? ws_size - state_bytes : 0;
    const size_t z_bytes_per_t = (size_t)B_DIM * NQ * sizeof(float4);   // 256 KiB
    int maxChunkT = (int)(avail / z_bytes_per_t);
    if (maxChunkT > T_DIM) maxChunkT = T_DIM;
    maxChunkT &= ~15;                  // recur requires multiples of 16
    if (maxChunkT < 16) maxChunkT = 16; // ws assumed >= ~4.2 MiB

    int t0 = 0;
    int first = 1;
    while (t0 < T_DIM) {
        int ct = (T_DIM - t0 < maxChunkT) ? (T_DIM - t0) : maxChunkT;
        int rows = ct * B_DIM;
        qlstm_gemm<<<rows / ROWS_PER_BLK, 256, 0, stream>>>(
            X + (size_t)t0 * B_DIM * D_IN_DIM,
            Wf, Wi, Wg, Wo, bf, bi, bg, bo, thf, thi, thg, tho,
            Zbuf);
        int last = (t0 + ct == T_DIM) ? 1 : 0;
        qlstm_recur<<<(B_DIM * NQ) / 64, 64, 0, stream>>>(
            Zbuf, Wf, Wi, Wg, Wo, out, state, t0, ct, first, last);
        t0 += ct;
        first = 0;
    }
}

// Round 5
// 459.425 us; speedup vs baseline: 1.6294x; 1.0602x over previous
//
#include <hip/hip_runtime.h>

#define T_DIM 256
#define B_DIM 2048
#define D_IN_DIM 128
#define NQ 8
#define ROWS_PER_BLK 64
#define XSTRIDE 129   // X tile pad: bank = (row + k) % 32 -> 2-way, free
#define TSTRIDE 33    // transpose tile pad: 2-way, free

// ---------------------------------------------------------------------------
// Kernel 1: Z[row][q] = float4(f,i,g,o) of x[row].Wg[:,q] + b_g[q] + th_g[q]
// Block = 256 thr = 4 waves; wave = gate, lane = row-in-tile. X staged in LDS
// (coalesced float4), W streamed through scalar loads (wave-uniform index),
// epilogue transposes through LDS so the global store is coalesced float4 in
// the recurrence-friendly [row][q][gate] layout. (~63 us, memory-bound.)
// ---------------------------------------------------------------------------
__global__ __launch_bounds__(256) void qlstm_gemm(
    const float* __restrict__ X,   // chunk base, [rows][128]
    const float* __restrict__ Wf, const float* __restrict__ Wi,
    const float* __restrict__ Wg, const float* __restrict__ Wo,
    const float* __restrict__ bf, const float* __restrict__ bi,
    const float* __restrict__ bg, const float* __restrict__ bo,
    const float* __restrict__ thf, const float* __restrict__ thi,
    const float* __restrict__ thg, const float* __restrict__ tho,
    float4* __restrict__ Z)        // [rows][8] float4
{
    __shared__ float xs[ROWS_PER_BLK * XSTRIDE];   // 33 KB, reused for transpose

    const int t = (int)threadIdx.x;
    const int r0 = (int)blockIdx.x * ROWS_PER_BLK;

    const float4* Xg = (const float4*)(X + (size_t)r0 * D_IN_DIM);
#pragma unroll
    for (int i = 0; i < 8; i++) {
        int L = t + i * 256;
        float4 v = Xg[L];
        int row = L >> 5;
        int k4  = L & 31;
        float* d = &xs[row * XSTRIDE + k4 * 4];
        d[0] = v.x; d[1] = v.y; d[2] = v.z; d[3] = v.w;
    }
    __syncthreads();

    const int wid  = __builtin_amdgcn_readfirstlane(t >> 6);  // wave id = gate
    const int lane = t & 63;                                   // row in tile

    const float* W  = (wid == 0) ? Wf  : (wid == 1) ? Wi  : (wid == 2) ? Wg  : Wo;
    const float* BB = (wid == 0) ? bf  : (wid == 1) ? bi  : (wid == 2) ? bg  : bo;
    const float* TH = (wid == 0) ? thf : (wid == 1) ? thi : (wid == 2) ? thg : tho;

    float acc[NQ];
#pragma unroll
    for (int q = 0; q < NQ; q++) acc[q] = BB[q] + TH[q];

    const float* xrow = &xs[lane * XSTRIDE];
#pragma unroll 4
    for (int k = 0; k < D_IN_DIM; k++) {
        float xk = xrow[k];
#pragma unroll
        for (int q = 0; q < NQ; q++)
            acc[q] += xk * W[k * NQ + q];
    }

    __syncthreads();
    float* tile = xs;   // [64][TSTRIDE], elem (r, q*4+g)
#pragma unroll
    for (int q = 0; q < NQ; q++)
        tile[lane * TSTRIDE + q * 4 + wid] = acc[q];
    __syncthreads();

    float4* Zblk = Z + (size_t)r0 * NQ;
#pragma unroll
    for (int i = 0; i < 2; i++) {
        int F = t + i * 256;          // float4 index: r = F>>3, q = F&7
        int r = F >> 3, q = F & 7;
        const float* s = &tile[r * TSTRIDE + q * 4];
        Zblk[F] = make_float4(s[0], s[1], s[2], s[3]);
    }
}

// ---------------------------------------------------------------------------
// Kernel 2: sequential recurrence. 256 blocks x 64 thr (1 wave/CU).
// THIS ROUND: transcendentals forced to raw HW ops (v_cos / v_exp / v_rcp)
// via __builtin_amdgcn_* — __cosf/__expf were lowering to multi-instruction
// library code and dominating the per-step critical path (~1500 cyc/step).
// Ping-pong register double buffer kept; sched_barrier(0) pins the prefetch
// issue points so the scheduler can't sink loads to their uses.
// ---------------------------------------------------------------------------
#define INV_2PI 0.15915494309189535f
#define L2E     1.4426950408889634f

__device__ __forceinline__ float hw_cos(float x) {
    return __builtin_amdgcn_cosf(x * INV_2PI);        // v_cos takes revolutions
}
__device__ __forceinline__ float hw_sig(float x) {
    return __builtin_amdgcn_rcpf(1.0f + __builtin_amdgcn_exp2f(-L2E * x));
}
__device__ __forceinline__ float hw_tanh(float x) {
    return 1.0f - 2.0f * __builtin_amdgcn_rcpf(__builtin_amdgcn_exp2f((2.0f * L2E) * x) + 1.0f);
}

#define BCAST8(x, J) \
    __int_as_float(__builtin_amdgcn_ds_swizzle(__float_as_int(x), ((J) << 5) | 0x18))

#define DOT_TERM(J) { \
    float hj = BCAST8(h, J); \
    accf += hj * whf[J]; acci += hj * whi[J]; \
    accg += hj * whg[J]; acco += hj * who[J]; }

#define LSTM_STEP(zv, outp) { \
    float accf = (zv).x, acci = (zv).y, accg = (zv).z, acco = (zv).w; \
    DOT_TERM(0) DOT_TERM(1) DOT_TERM(2) DOT_TERM(3) \
    DOT_TERM(4) DOT_TERM(5) DOT_TERM(6) DOT_TERM(7) \
    float fg = hw_sig(hw_cos(accf)); \
    float ig = hw_sig(hw_cos(acci)); \
    float gg = hw_tanh(hw_cos(accg)); \
    float og = hw_sig(hw_cos(acco)); \
    c = fg * c + ig * gg; \
    h = og * hw_tanh(c); \
    *(outp) = h; }

__global__ __launch_bounds__(64) void qlstm_recur(
    const float4* __restrict__ Z,  // chunk base, [ct][B*NQ] float4
    const float* __restrict__ Wf, const float* __restrict__ Wi,
    const float* __restrict__ Wg, const float* __restrict__ Wo,
    float* __restrict__ out,       // full output base
    float* __restrict__ state,     // [h: B*8][c: B*8]
    int t0, int ct, int first, int last)
{
    const int tid = (int)blockIdx.x * 64 + (int)threadIdx.x;  // 0..16383
    const int q   = tid & 7;

    float whf[8], whi[8], whg[8], who[8];
#pragma unroll
    for (int j = 0; j < 8; j++) {
        whf[j] = Wf[(D_IN_DIM + j) * NQ + q];
        whi[j] = Wi[(D_IN_DIM + j) * NQ + q];
        whg[j] = Wg[(D_IN_DIM + j) * NQ + q];
        who[j] = Wo[(D_IN_DIM + j) * NQ + q];
    }

    float h, c;
    if (first) { h = 0.0f; c = 0.0f; }
    else       { h = state[tid]; c = state[B_DIM * NQ + tid]; }

    const size_t stepsz = (size_t)B_DIM * NQ;   // 16384
    const float4* Zp = Z + tid;
    float* outp = out + (size_t)t0 * stepsz + tid;

    float4 bufA[8], bufB[8];
    // Prologue: fill A with steps 0..7 (ct is a multiple of 16, >= 16).
#pragma unroll
    for (int s = 0; s < 8; s++) bufA[s] = Zp[(size_t)s * stepsz];

    for (int tb = 0; tb < ct; tb += 16) {
        // Issue loads for steps tb+8..tb+15 into B.
#pragma unroll
        for (int s = 0; s < 8; s++) bufB[s] = Zp[(size_t)(tb + 8 + s) * stepsz];
        __builtin_amdgcn_sched_barrier(0);   // pin: loads stay issued here
        // Consume A: steps tb..tb+7.
#pragma unroll
        for (int s = 0; s < 8; s++) {
            float4 z = bufA[s];
            LSTM_STEP(z, outp)
            outp += stepsz;
        }
        // Issue loads for steps tb+16..tb+23 into A (skip on last group).
        if (tb + 16 < ct) {
#pragma unroll
            for (int s = 0; s < 8; s++) bufA[s] = Zp[(size_t)(tb + 16 + s) * stepsz];
        }
        __builtin_amdgcn_sched_barrier(0);
        // Consume B: steps tb+8..tb+15.
#pragma unroll
        for (int s = 0; s < 8; s++) {
            float4 z = bufB[s];
            LSTM_STEP(z, outp)
            outp += stepsz;
        }
    }

    if (last) {
        out[(size_t)T_DIM * stepsz + tid] = h;
        out[(size_t)T_DIM * stepsz + stepsz + tid] = c;
    } else {
        state[tid] = h;
        state[B_DIM * NQ + tid] = c;
    }
}

// ---------------------------------------------------------------------------
extern "C" void kernel_launch(void* const* d_in, const int* in_sizes, int n_in,
                              void* d_out, int out_size, void* d_ws, size_t ws_size,
                              hipStream_t stream) {
    const float* X   = (const float*)d_in[0];
    const float* Wf  = (const float*)d_in[1];
    const float* bf  = (const float*)d_in[2];
    const float* Wi  = (const float*)d_in[3];
    const float* bi  = (const float*)d_in[4];
    const float* Wg  = (const float*)d_in[5];
    const float* bg  = (const float*)d_in[6];
    const float* Wo  = (const float*)d_in[7];
    const float* bo  = (const float*)d_in[8];
    const float* thf = (const float*)d_in[9];
    const float* thi = (const float*)d_in[10];
    const float* thg = (const float*)d_in[11];
    const float* tho = (const float*)d_in[12];
    float* out = (float*)d_out;

    const size_t state_bytes = (size_t)2 * B_DIM * NQ * sizeof(float);  // 128 KiB
    float* state = (float*)d_ws;
    float4* Zbuf = (float4*)((char*)d_ws + state_bytes);
    size_t avail = ws_size > state_bytes ? ws_size - state_bytes : 0;
    const size_t z_bytes_per_t = (size_t)B_DIM * NQ * sizeof(float4);   // 256 KiB
    int maxChunkT = (int)(avail / z_bytes_per_t);
    if (maxChunkT > T_DIM) maxChunkT = T_DIM;
    maxChunkT &= ~15;                  // recur requires multiples of 16
    if (maxChunkT < 16) maxChunkT = 16; // ws assumed >= ~4.2 MiB

    int t0 = 0;
    int first = 1;
    while (t0 < T_DIM) {
        int ct = (T_DIM - t0 < maxChunkT) ? (T_DIM - t0) : maxChunkT;
        int rows = ct * B_DIM;
        qlstm_gemm<<<rows / ROWS_PER_BLK, 256, 0, stream>>>(
            X + (size_t)t0 * B_DIM * D_IN_DIM,
            Wf, Wi, Wg, Wo, bf, bi, bg, bo, thf, thi, thg, tho,
            Zbuf);
        int last = (t0 + ct == T_DIM) ? 1 : 0;
        qlstm_recur<<<(B_DIM * NQ) / 64, 64, 0, stream>>>(
            Zbuf, Wf, Wi, Wg, Wo, out, state, t0, ct, first, last);
        t0 += ct;
        first = 0;
    }
}